// Round 13
// baseline (102.327 us; speedup 1.0000x reference)
//
#include <hip/hip_runtime.h>
#include <math.h>

#define B_SZ 2048
#define R_SZ 64
#define QT 8                    // q rows per kde block
#define KDE_BLOCKS (B_SZ / QT)  // 256 blocks x 16 waves

#define B_POW_NEG02 0.217637640824031f   // 2048^-0.2 = 2^-2.2
#define SQRT_2PI 2.5066282746310002f
#define LOG2E 1.44269504088896340736f

// native v_exp_f32 (exp2)
extern "C" __device__ float __ocml_native_exp2_f32(float);

typedef __attribute__((ext_vector_type(2))) float f32x2;  // -> v_pk_* f32 ops

// ---------------------------------------------------------------------------
// ws layout (floats):
//   [0:64)    cov_partial
//   [96]      ent_acc   (own line)
//   [128]     done2     (int, own line)
//   [256:256+131072)   U2: s-tiled transposed prescaled input, 512 KB.
//       U2[g*256 + r*4 + s2] = A[(4g+s2)*64 + r] * kscale[r],  g=s>>2, s2=s&3
//       => lane r's float4 at F4[g*64+r] holds its 4 next s-samples;
//          a wave-load of F4[g*64 + (0..63)] is 1 KB contiguous.
//   [131328:...)       density[2048][64]  (plain stores, exclusive rows)
// ---------------------------------------------------------------------------

// Kernel 1: column stats -> kscale, then prescale+repack A into U2.
// 64 blocks x 1024. Each block: full column-sum pass (deterministic),
// then writes U2 slab [i*2048, (i+1)*2048) (perfectly coalesced stores).
__global__ __launch_bounds__(1024) void prescale_kernel(const float* __restrict__ A,
                                                        float* __restrict__ U2,
                                                        float* __restrict__ ent_acc,
                                                        int* __restrict__ done2) {
    int i = blockIdx.x;
    int tid = threadIdx.x;
    int r = tid & 63, sg = tid >> 6;

    // full column sums (wave sg covers rows [128*sg, 128*sg+128))
    float s = 0.f, s2 = 0.f;
    {
        const float* Ac = A + sg * (128 * R_SZ) + r;
#pragma unroll 8
        for (int b = 0; b < 128; ++b) {
            float v = Ac[b * R_SZ];
            s += v;
            s2 = fmaf(v, v, s2);
        }
    }
    __shared__ float sred[16][64], s2red[16][64];
    __shared__ float ksh[64];
    sred[sg][r] = s; s2red[sg][r] = s2;
    __syncthreads();
    if (tid < 64) {
        float S = 0.f, S2 = 0.f;
#pragma unroll
        for (int t = 0; t < 16; ++t) { S += sred[t][tid]; S2 += s2red[t][tid]; }
        float m = S * (1.f / (float)B_SZ);
        float var = (S2 - S * m) * (1.f / (float)(B_SZ - 1));   // ddof=1
        var = fmaxf(var, 0.f);
        float h = fmaxf(1.06f * sqrtf(var) * B_POW_NEG02, 1e-4f);
        ksh[tid] = sqrtf(0.5f * LOG2E) / h;   // exp2(-(k*d)^2) = exp(-0.5(d/h)^2)
    }
    if (i == 0 && tid == 64) { *ent_acc = 0.f; *done2 = 0; }
    __syncthreads();

    // repack+prescale: dglob in [i*2048, i*2048+2048), 2 per thread
#pragma unroll
    for (int rep = 0; rep < 2; ++rep) {
        int dglob = i * 2048 + rep * 1024 + tid;
        int rr = (dglob >> 2) & 63;
        int ss = ((dglob >> 8) << 2) | (dglob & 3);
        U2[dglob] = A[ss * R_SZ + rr] * ksh[rr];
    }
}

// ---------------------------------------------------------------------------
// Kernel 2: pairwise KDE, QT=8, float4 s-loads (4x fewer load instrs).
// 256 blocks x 1024 thr. Wave sg consumes s-groups G = sg + 16m, m=0..31;
// each float4 load delivers 4 s-samples for this lane. Depth-4 float4
// prefetch (16 rows in flight). No stats, no k-mul (prescaled), no
// barriers/atomics in the loop. Density rows: plain exclusive stores.
// ---------------------------------------------------------------------------
__global__ __launch_bounds__(1024) void kde_kernel(const float* __restrict__ U2,
                                                   float* __restrict__ density) {
    int tid = threadIdx.x;
    int r = tid & 63, sg = tid >> 6;
    int q0 = blockIdx.x * QT;

    // q fragments from the tiled layout: U2[(q>>2)*256 + r*4 + (q&3)]
#define QLD(j) U2[((q0 + (j)) >> 2) * 256 + r * 4 + ((q0 + (j)) & 3)]
    f32x2 uq01 = { QLD(0), QLD(1) };
    f32x2 uq23 = { QLD(2), QLD(3) };
    f32x2 uq45 = { QLD(4), QLD(5) };
    f32x2 uq67 = { QLD(6), QLD(7) };
#undef QLD
    f32x2 c01 = { 0.f, 0.f }, c23 = { 0.f, 0.f };
    f32x2 c45 = { 0.f, 0.f }, c67 = { 0.f, 0.f };

#define KDE_BODY(usv)                                                          \
    {                                                                          \
        f32x2 uss = { (usv), (usv) };                                          \
        f32x2 d01 = uq01 - uss, d23 = uq23 - uss;                              \
        f32x2 d45 = uq45 - uss, d67 = uq67 - uss;                              \
        f32x2 n01 = -d01 * d01, n23 = -d23 * d23;                              \
        f32x2 n45 = -d45 * d45, n67 = -d67 * d67;                              \
        f32x2 e01 = { __ocml_native_exp2_f32(n01.x), __ocml_native_exp2_f32(n01.y) }; \
        f32x2 e23 = { __ocml_native_exp2_f32(n23.x), __ocml_native_exp2_f32(n23.y) }; \
        f32x2 e45 = { __ocml_native_exp2_f32(n45.x), __ocml_native_exp2_f32(n45.y) }; \
        f32x2 e67 = { __ocml_native_exp2_f32(n67.x), __ocml_native_exp2_f32(n67.y) }; \
        c01 += e01; c23 += e23; c45 += e45; c67 += e67;                        \
    }
#define GROUP(v) { KDE_BODY((v).x); KDE_BODY((v).y); KDE_BODY((v).z); KDE_BODY((v).w); }

    // wave sg: s-groups G = sg + 16m, m = 0..31; F4 stride per m = 1024
    const float4* F4 = (const float4*)U2;
    const float4* Up = F4 + sg * 64 + r;
    float4 p0 = Up[0];
    float4 p1 = Up[1024];
    float4 p2 = Up[2048];
    float4 p3 = Up[3072];

    int li = 4096;
#pragma unroll 1
    for (int m = 0; m < 7; ++m) {                 // 7 x 4 groups = 28 consumed
        float4 u0 = p0; p0 = Up[li];          GROUP(u0);
        float4 u1 = p1; p1 = Up[li + 1024];   GROUP(u1);
        float4 u2 = p2; p2 = Up[li + 2048];   GROUP(u2);
        float4 u3 = p3; p3 = Up[li + 3072];   GROUP(u3);
        li += 4096;
    }
    GROUP(p0); GROUP(p1); GROUP(p2); GROUP(p3);   // drain last 4 groups

#undef GROUP
#undef KDE_BODY

    // cross-wave reduction, then PLAIN stores of the 8 owned rows
    __shared__ float red[16][QT][64];             // 32 KB
    red[sg][0][r] = c01.x; red[sg][1][r] = c01.y;
    red[sg][2][r] = c23.x; red[sg][3][r] = c23.y;
    red[sg][4][r] = c45.x; red[sg][5][r] = c45.y;
    red[sg][6][r] = c67.x; red[sg][7][r] = c67.y;
    __syncthreads();
    if (sg < QT) {                                // wave sg: row q0+sg
        float S = 0.f;
#pragma unroll
        for (int t = 0; t < 16; ++t) S += red[t][sg][r];
        density[(q0 + sg) * R_SZ + r] = S;        // exclusive row
    }
}

// ---------------------------------------------------------------------------
// Kernel 3: epilogue — Gram row + cov row + lscale + entropy + final fold.
// (unchanged from R12 — verified correct)
// ---------------------------------------------------------------------------
__global__ __launch_bounds__(1024) void epilogue_kernel(const float* __restrict__ A,
                                                        const float* __restrict__ density,
                                                        float* __restrict__ cov_partial,
                                                        float* __restrict__ ent_acc,
                                                        int* __restrict__ done2,
                                                        float* __restrict__ out) {
    int i = blockIdx.x;
    int tid = threadIdx.x;
    int j = tid & 63, bg = tid >> 6;          // 16 b-groups

    float g = 0.f, sj = 0.f, s2j = 0.f;
#pragma unroll 4
    for (int b = bg; b < B_SZ; b += 16) {
        float ai = A[b * R_SZ + i];           // wave-uniform broadcast
        float aj = A[b * R_SZ + j];           // coalesced
        g = fmaf(ai, aj, g);
        sj += aj;
        s2j = fmaf(aj, aj, s2j);
    }

    __shared__ float gred[16][64], sred[16][64], s2red[16][64];
    __shared__ float gfin[64], sfin[64], lsh[64];
    gred[bg][j] = g; sred[bg][j] = sj; s2red[bg][j] = s2j;
    __syncthreads();
    if (tid < 64) {
        float G = 0.f, S = 0.f, S2 = 0.f;
#pragma unroll
        for (int t = 0; t < 16; ++t) { G += gred[t][j]; S += sred[t][j]; S2 += s2red[t][j]; }
        gfin[j] = G;
        sfin[j] = S;
        float m = S * (1.f / (float)B_SZ);
        float var = (S2 - S * m) * (1.f / (float)(B_SZ - 1));   // ddof=1
        var = fmaxf(var, 0.f);
        float h = fmaxf(1.06f * sqrtf(var) * B_POW_NEG02, 1e-4f);
        lsh[j] = 1.0f / ((float)B_SZ * h * SQRT_2PI);
    }
    __syncthreads();
    if (tid < 64) {                            // covariance row i
        float m_j = sfin[j] * (1.f / (float)B_SZ);
        float m_i = sfin[i] * (1.f / (float)B_SZ);
        float cov = (gfin[j] - (float)B_SZ * m_i * m_j) * (1.f / (float)(B_SZ - 1));
        float v = (j == i) ? 0.f : cov * cov;
        for (int off = 32; off > 0; off >>= 1) v += __shfl_down(v, off, 64);
        if (j == 0) cov_partial[i] = v;
    }

    // entropy over density rows [32i, 32i+32): 2048 elems, 2 per thread
    float ls = lsh[j];
    int f = i * 2048 + tid;
    float v = __logf(fmaf(density[f], ls, 1e-8f))
            + __logf(fmaf(density[f + 1024], ls, 1e-8f));
    for (int off = 32; off > 0; off >>= 1) v += __shfl_down(v, off, 64);
    __shared__ float wr[16];
    if (j == 0) wr[bg] = v;
    __syncthreads();
    __shared__ int lastflag;
    if (tid == 0) {
        float sE = 0.f;
#pragma unroll
        for (int w = 0; w < 16; ++w) sE += wr[w];
        atomicAdd(ent_acc, sE);            // once per block (CAS fine here)
        __threadfence();
        int prev = atomicAdd(done2, 1);
        lastflag = (prev == 63);
    }
    __syncthreads();
    if (lastflag && tid < 64) {            // grid-final fold in last block
        __threadfence();
        float v2 = cov_partial[tid];
        for (int off = 32; off > 0; off >>= 1) v2 += __shfl_down(v2, off, 64);
        if (tid == 0) {
            float ent = __hip_atomic_load(ent_acc, __ATOMIC_ACQUIRE,
                                          __HIP_MEMORY_SCOPE_AGENT);
            out[0] = ent * (1.0f / ((float)B_SZ * (float)R_SZ)) + v2;
        }
    }
}

extern "C" void kernel_launch(void* const* d_in, const int* in_sizes, int n_in,
                              void* d_out, int out_size, void* d_ws, size_t ws_size,
                              hipStream_t stream) {
    const float* A = (const float*)d_in[0];
    float* out = (float*)d_out;

    float* wsf = (float*)d_ws;
    float* cov_partial = wsf;                 // 64
    float* ent_acc     = wsf + 96;            // isolated line
    int*   done2       = (int*)(wsf + 128);
    float* U2          = wsf + 256;           // 2048*64, tiled layout
    float* density     = wsf + 256 + B_SZ * R_SZ;

    prescale_kernel<<<R_SZ, 1024, 0, stream>>>(A, U2, ent_acc, done2);
    kde_kernel<<<KDE_BLOCKS, 1024, 0, stream>>>(U2, density);
    epilogue_kernel<<<R_SZ, 1024, 0, stream>>>(A, density, cov_partial,
                                               ent_acc, done2, out);
}